// Round 8
// baseline (150.414 us; speedup 1.0000x reference)
//
#include <hip/hip_runtime.h>
#include <math.h>
#include <stdint.h>

#define ALPHA 0.2f

typedef __attribute__((ext_vector_type(8)))  short bf16x8;
typedef __attribute__((ext_vector_type(4)))  float f32x4;
typedef __attribute__((ext_vector_type(16))) float f32x16;

__device__ __forceinline__ uint32_t pack_bf16(float a, float b) {
    return ((__float_as_uint(a) + 0x8000u) >> 16) |
           ((__float_as_uint(b) + 0x8000u) & 0xFFFF0000u);
}

// ---------------------------------------------------------------------------
// Kernel 1: k_wh — Wh = (x^T)W fused transpose-GEMM, emitting Wh directly in
// mfma_f32_32x32x16_bf16 B-fragment layout, plus fp32 Wh1/Wh2 score vectors.
// GEMM core unchanged from r6/r7; only the frag store is relaid:
//   frag (kf = jt, ntile = nt>>1): element (j' = q*4+jj, n = (nt&1)*16+om)
//   -> lane = 32*(q>>1) | (nt&1)<<4 | om, elements (q&1)*4..+3 = uint2 at
//      byte 8*(q&1). Whf uint4-index = ((bt*4 + ntile)*64 + kf)*64 + lane.
// ---------------------------------------------------------------------------
__global__ __launch_bounds__(512) void k_wh(const float* __restrict__ x,
                                            const float* __restrict__ W,
                                            const float* __restrict__ a,
                                            uint4* __restrict__ Whf,
                                            float* __restrict__ Wh1,
                                            float* __restrict__ Wh2) {
    __shared__ float xs[16 * 512];        // 32 KB
    __shared__ float Wv[128 * 68];        // 34.8 KB

    const int tid = threadIdx.x;
    const int b   = blockIdx.x & 7;
    const int jt  = blockIdx.x >> 3;      // 0..63 (16-row tiles)

    const float4* xg4 = (const float4*)(x + (size_t)(b * 1024 + jt * 16) * 512);
    #pragma unroll
    for (int i = 0; i < 4; ++i) {
        int    idx = tid + i * 512;       // 0..2047
        float4 v   = xg4[idx];
        int jl  = idx >> 7;
        int rem = idx & 127;
        int f   = rem >> 1;
        int tq  = rem & 1;
        int kk  = f ^ ((jl >> 2) << 2);
        float* dst = &xs[jl * 512 + (tq * 4) * 64 + kk];
        dst[0]   = v.x;
        dst[64]  = v.y;
        dst[128] = v.z;
        dst[192] = v.w;
    }
    const float4* Wg4 = (const float4*)W;
    #pragma unroll
    for (int i = 0; i < 4; ++i) {
        int    idx = tid + i * 512;       // 0..2047
        float4 v   = Wg4[idx];
        int k  = idx >> 5;
        int o0 = (idx & 31) * 4;
        #pragma unroll
        for (int c = 0; c < 4; ++c) {
            int o   = o0 + c;
            int adr = o * 68 + ((((k >> 2) ^ ((o >> 3) & 7)) << 2) | (k & 3));
            Wv[adr] = (&v.x)[c];
        }
    }
    __syncthreads();

    const int w  = tid >> 6;              // wave = t (0..7)
    const int l  = tid & 63;
    const int q  = l >> 4;
    const int om = l & 15;
    const int t  = w;

    float acc[4][8];
    #pragma unroll
    for (int jj = 0; jj < 4; ++jj)
        #pragma unroll
        for (int nt = 0; nt < 8; ++nt) acc[jj][nt] = 0.f;

    for (int kc = 0; kc < 64; kc += 4) {
        float4 xv[4], wv[8];
        const int kx = kc ^ (q << 2);
        #pragma unroll
        for (int jj = 0; jj < 4; ++jj)
            xv[jj] = *(const float4*)&xs[(q * 4 + jj) * 512 + t * 64 + kx];
        #pragma unroll
        for (int nt = 0; nt < 8; ++nt) {
            int og  = nt * 16 + om;
            int grp = (kc >> 2) ^ ((nt * 2 + (om >> 3)) & 7);
            wv[nt]  = *(const float4*)&Wv[og * 68 + grp * 4];
        }
        #pragma unroll
        for (int jj = 0; jj < 4; ++jj) {
            #pragma unroll
            for (int nt = 0; nt < 8; ++nt) {
                float s = acc[jj][nt];
                s = fmaf(xv[jj].x, wv[nt].x, s);
                s = fmaf(xv[jj].y, wv[nt].y, s);
                s = fmaf(xv[jj].z, wv[nt].z, s);
                s = fmaf(xv[jj].w, wv[nt].w, s);
                acc[jj][nt] = s;
            }
        }
    }

    const int bt = b * 8 + t;

    float a1v[8], a2v[8];
    #pragma unroll
    for (int nt = 0; nt < 8; ++nt) {
        a1v[nt] = a[nt * 16 + om];
        a2v[nt] = a[128 + nt * 16 + om];
    }
    #pragma unroll
    for (int jj = 0; jj < 4; ++jj) {
        float s1 = 0.f, s2 = 0.f;
        #pragma unroll
        for (int nt = 0; nt < 8; ++nt) {
            s1 = fmaf(acc[jj][nt], a1v[nt], s1);
            s2 = fmaf(acc[jj][nt], a2v[nt], s2);
        }
        #pragma unroll
        for (int off = 1; off < 16; off <<= 1) {
            s1 += __shfl_xor(s1, off);
            s2 += __shfl_xor(s2, off);
        }
        if (om == 0) {
            int j = jt * 16 + q * 4 + jj;
            Wh1[bt * 1024 + j] = s1;
            Wh2[bt * 1024 + j] = s2;
        }
    }

    // 32x32x16 B-frag store (see header comment)
    #pragma unroll
    for (int nt = 0; nt < 8; ++nt) {
        uint2 st;
        st.x = pack_bf16(acc[0][nt], acc[1][nt]);
        st.y = pack_bf16(acc[2][nt], acc[3][nt]);
        int    lane2 = ((q >> 1) << 5) | ((nt & 1) << 4) | om;
        size_t fidx  = ((size_t)(bt * 4 + (nt >> 1)) * 64 + jt) * 64 + lane2;
        char*  p     = (char*)(Whf + fidx) + ((q & 1) << 3);
        *(uint2*)p = st;
    }
}

// ---------------------------------------------------------------------------
// Kernel 2: adj -> bitmask adjq laid out for the 32x32 consumer:
//   byte for (i, jg = j>>3) at  i*128 + (jg&1)*64 + ((jg>>1)&1)*32 + (jg>>2)
//   (jg = s*4 + h*2 + g  ->  [g][h][s]); lane (i,g) reads 64 contiguous B.
// ---------------------------------------------------------------------------
__global__ __launch_bounds__(256) void k_adjb(const float* __restrict__ adj,
                                              unsigned char* __restrict__ adjq) {
    int idx = blockIdx.x * 256 + threadIdx.x;       // 0..131071
    int i   = idx >> 7;
    int pos = idx & 127;                            // jg
    const float4* a4 = (const float4*)adj + idx * 2;
    float4 v0 = a4[0], v1 = a4[1];
    unsigned int by = 0;
    by |= (v0.x > 0.f) ? 1u : 0u;
    by |= (v0.y > 0.f) ? 2u : 0u;
    by |= (v0.z > 0.f) ? 4u : 0u;
    by |= (v0.w > 0.f) ? 8u : 0u;
    by |= (v1.x > 0.f) ? 16u : 0u;
    by |= (v1.y > 0.f) ? 32u : 0u;
    by |= (v1.z > 0.f) ? 64u : 0u;
    by |= (v1.w > 0.f) ? 128u : 0u;
    adjq[(i << 7) + ((pos & 1) << 6) + (((pos >> 1) & 1) << 5) + (pos >> 2)] = (unsigned char)by;
}

// ---------------------------------------------------------------------------
// Kernel 3: k_agg — dense flash aggregation with 32-row waves.
// ROUND-8: mfma_f32_32x32x16_bf16, 4 waves x 32 rows -> per-CU B-frag LDS
// traffic halved vs r7 (8 waves read the tile, not 16); E|F packed as bf16
// pair (4 B/j) halves efs reads; supersteps of 64 j (16 barriers, 32 KB
// dbuf) amortize the per-step barrier drain that bounded r6.
// Layouts: A/B: idx=lane&31, k=(lane>>5)*8+e; D: col=lane&31,
// row=(reg&3)+8*(reg>>2)+4*(lane>>5). l_i via ones-MFMA (same D rows).
// Grid 512: blockIdx = ((itile*8 + t)*8 + b) -> XCD = b.
// ---------------------------------------------------------------------------
__global__ __launch_bounds__(256) void k_agg(const uint4* __restrict__ Whf,
                                             const float* __restrict__ Wh1,
                                             const float* __restrict__ Wh2,
                                             const unsigned char* __restrict__ adjq,
                                             float* __restrict__ out) {
    __shared__ __attribute__((aligned(16))) uint4    bstage[2][1024];  // 32 KB
    __shared__ __attribute__((aligned(16))) uint32_t efs[1024];        // 4 KB bf16 E|F
    __shared__ float wh1s[128];
    __shared__ float m2s[4];

    const int tid   = threadIdx.x;
    const int b     = blockIdx.x & 7;
    const int t     = (blockIdx.x >> 3) & 7;
    const int itile = blockIdx.x >> 6;            // 0..7
    const int bt    = b * 8 + t;
    const int i0    = itile * 128;

    const int w   = tid >> 6;                     // wave 0..3
    const int l   = tid & 63;
    const int col = l & 31;
    const int g   = l >> 5;                       // k-half group
    const int row = w * 32 + col;                 // block-local i-row

    const uint4* plane = Whf + (size_t)bt * 16384;
    const int    c     = w;                       // staging chunk = ntile
    const int    li    = l;

    // prefetch superstep 0 (kf 0..3)
    uint4 pf[4];
    #pragma unroll
    for (int f = 0; f < 4; ++f) pf[f] = plane[(c * 64 + f) * 64 + li];

    // adj mask regs: 64 B at (i0+row)*128 + g*64
    const uint4* ap = (const uint4*)(adjq + ((size_t)(i0 + row) << 7) + (g << 6));
    uint4 am[4];
    #pragma unroll
    for (int f = 0; f < 4; ++f) am[f] = ap[f];

    // stage E|F (bf16-packed) + running max of h2; Wh1 slice
    const float* wh2g = Wh2 + bt * 1024;
    float mx = -1e30f;
    #pragma unroll
    for (int rep = 0; rep < 4; ++rep) {
        int   j  = tid + rep * 256;
        float h2 = wh2g[j];
        float E  = __expf(h2);
        float F  = __expf(ALPHA * h2);
        efs[j] = pack_bf16(E, F);
        mx = fmaxf(mx, h2);
    }
    #pragma unroll
    for (int off = 1; off < 64; off <<= 1) mx = fmaxf(mx, __shfl_xor(mx, off));
    if (l == 0) m2s[w] = mx;
    if (tid < 128) wh1s[tid] = Wh1[bt * 1024 + i0 + tid];

    #pragma unroll
    for (int f = 0; f < 4; ++f) bstage[0][(c * 4 + f) * 64 + li] = pf[f];
    __syncthreads();

    const float M2 = fmaxf(fmaxf(m2s[0], m2s[1]), fmaxf(m2s[2], m2s[3]));
    const float h1 = wh1s[row];
    const float e0 = h1 + M2;
    const float mp = fmaxf(e0, ALPHA * e0);       // p <= 1 for all (i,j)
    const float Af = __expf(h1 - mp);
    const float Bf = __expf(ALPHA * h1 - mp);
    const float G  = __expf(-h1);

    f32x16 acc[4];
    #pragma unroll
    for (int nt2 = 0; nt2 < 4; ++nt2)
        #pragma unroll
        for (int r = 0; r < 16; ++r) acc[nt2][r] = 0.f;
    f32x16 accl;
    #pragma unroll
    for (int r = 0; r < 16; ++r) accl[r] = 0.f;

    bf16x8 ones;
    #pragma unroll
    for (int i = 0; i < 8; ++i) ones[i] = (short)0x3F80;

    #pragma unroll
    for (int u = 0; u < 16; ++u) {
        if (u + 1 < 16) {
            #pragma unroll
            for (int f = 0; f < 4; ++f)
                pf[f] = plane[(c * 64 + (u + 1) * 4 + f) * 64 + li];
        }

        #pragma unroll
        for (int d = 0; d < 2; ++d) {             // j-step s = u*2+d (32 j)
            const int s = u * 2 + d;
            #pragma unroll
            for (int h = 0; h < 2; ++h) {         // 16-k MFMA slice
                const int jb = s * 32 + h * 16 + g * 8;
                uint4 efa = *(const uint4*)&efs[jb];
                uint4 efb = *(const uint4*)&efs[jb + 4];
                uint32_t ef[8] = {efa.x, efa.y, efa.z, efa.w,
                                  efb.x, efb.y, efb.z, efb.w};

                // adj byte: pe = h*32+s in lane's 64-byte window
                const int      pe = h * 32 + s;
                const uint4    av = am[pe >> 4];
                const int      cc = (pe >> 2) & 3;
                const uint32_t cw = (cc == 0) ? av.x : (cc == 1) ? av.y
                                   : (cc == 2) ? av.z : av.w;
                const uint32_t by = (cw >> ((pe & 3) * 8)) & 0xFFu;

                float p[8];
                #pragma unroll
                for (int e = 0; e < 8; ++e) {
                    float E  = __uint_as_float(ef[e] << 16);
                    float F  = __uint_as_float(ef[e] & 0xFFFF0000u);
                    bool  cd = E > G;                      // h1+h2 > 0
                    float pr = (cd ? Af : Bf) * (cd ? E : F);
                    p[e] = ((by >> e) & 1u) ? pr : 0.0f;
                }
                union { uint32_t u32[4]; bf16x8 v; } pk;
                #pragma unroll
                for (int r = 0; r < 4; ++r)
                    pk.u32[r] = pack_bf16(p[2 * r], p[2 * r + 1]);

                #pragma unroll
                for (int nt2 = 0; nt2 < 4; ++nt2) {
                    union { uint4 u4; bf16x8 v; } br;
                    br.u4 = bstage[u & 1][(nt2 * 4 + d * 2 + h) * 64 + l];
                    acc[nt2] = __builtin_amdgcn_mfma_f32_32x32x16_bf16(
                        pk.v, br.v, acc[nt2], 0, 0, 0);
                }
                accl = __builtin_amdgcn_mfma_f32_32x32x16_bf16(
                    pk.v, ones, accl, 0, 0, 0);
            }
        }

        if (u + 1 < 16) {
            #pragma unroll
            for (int f = 0; f < 4; ++f)
                bstage[(u + 1) & 1][(c * 4 + f) * 64 + li] = pf[f];
        }
        __syncthreads();
    }

    // epilogue: D rows r = (reg&3)+8*(reg>>2)+4*g; accl rows identical
    float* og = out + ((size_t)(b * 1024 + i0 + w * 32)) * 1024 + t;
    #pragma unroll
    for (int reg = 0; reg < 16; ++reg) {
        const int   r    = (reg & 3) + 8 * (reg >> 2) + 4 * g;
        const float linv = 1.0f / accl[reg];
        #pragma unroll
        for (int nt2 = 0; nt2 < 4; ++nt2) {
            float v = acc[nt2][reg] * linv;
            v = v > 0.f ? v : __expf(v) - 1.f;
            og[(size_t)r * 1024 + (nt2 * 32 + col) * 8] = v;
        }
    }
}

// ---------------------------------------------------------------------------
extern "C" void kernel_launch(void* const* d_in, const int* in_sizes, int n_in,
                              void* d_out, int out_size, void* d_ws, size_t ws_size,
                              hipStream_t stream) {
    const float* x   = (const float*)d_in[0];   // (8,1024,64,8)
    const float* adj = (const float*)d_in[1];   // (1024,1024)
    const float* W   = (const float*)d_in[2];   // (64,128)
    const float* a   = (const float*)d_in[3];   // (256,1)
    float* out = (float*)d_out;                 // (8,1024,128,8)

    uint4*         Whf  = (uint4*)d_ws;                        // 1048576 uint4 = 16 MB
    float*         Wh1  = (float*)(Whf + 1048576);             // 65536 f
    float*         Wh2  = Wh1 + 65536;                         // 65536 f
    unsigned char* adjq = (unsigned char*)(Wh2 + 65536);       // 131072 B

    k_wh  <<<512, 512, 0, stream>>>(x, W, a, Whf, Wh1, Wh2);
    k_adjb<<<512, 256, 0, stream>>>(adj, adjq);
    k_agg <<<512, 256, 0, stream>>>(Whf, Wh1, Wh2, adjq, out);
}

// Round 9
// 143.803 us; speedup vs baseline: 1.0460x; 1.0460x over previous
//
#include <hip/hip_runtime.h>
#include <math.h>
#include <stdint.h>

#define ALPHA 0.2f

typedef __attribute__((ext_vector_type(8)))  short bf16x8;
typedef __attribute__((ext_vector_type(4)))  float f32x4;
typedef __attribute__((ext_vector_type(16))) float f32x16;

__device__ __forceinline__ uint32_t pack_bf16(float a, float b) {
    return ((__float_as_uint(a) + 0x8000u) >> 16) |
           ((__float_as_uint(b) + 0x8000u) & 0xFFFF0000u);
}

// ---------------------------------------------------------------------------
// Kernel 1: k_wh — Wh = (x^T)W fused transpose-GEMM, emitting Wh directly in
// mfma_f32_32x32x16_bf16 B-fragment layout, plus fp32 Wh1/Wh2 score vectors.
// (unchanged from round 8)
// ---------------------------------------------------------------------------
__global__ __launch_bounds__(512) void k_wh(const float* __restrict__ x,
                                            const float* __restrict__ W,
                                            const float* __restrict__ a,
                                            uint4* __restrict__ Whf,
                                            float* __restrict__ Wh1,
                                            float* __restrict__ Wh2) {
    __shared__ float xs[16 * 512];        // 32 KB
    __shared__ float Wv[128 * 68];        // 34.8 KB

    const int tid = threadIdx.x;
    const int b   = blockIdx.x & 7;
    const int jt  = blockIdx.x >> 3;      // 0..63 (16-row tiles)

    const float4* xg4 = (const float4*)(x + (size_t)(b * 1024 + jt * 16) * 512);
    #pragma unroll
    for (int i = 0; i < 4; ++i) {
        int    idx = tid + i * 512;       // 0..2047
        float4 v   = xg4[idx];
        int jl  = idx >> 7;
        int rem = idx & 127;
        int f   = rem >> 1;
        int tq  = rem & 1;
        int kk  = f ^ ((jl >> 2) << 2);
        float* dst = &xs[jl * 512 + (tq * 4) * 64 + kk];
        dst[0]   = v.x;
        dst[64]  = v.y;
        dst[128] = v.z;
        dst[192] = v.w;
    }
    const float4* Wg4 = (const float4*)W;
    #pragma unroll
    for (int i = 0; i < 4; ++i) {
        int    idx = tid + i * 512;       // 0..2047
        float4 v   = Wg4[idx];
        int k  = idx >> 5;
        int o0 = (idx & 31) * 4;
        #pragma unroll
        for (int c = 0; c < 4; ++c) {
            int o   = o0 + c;
            int adr = o * 68 + ((((k >> 2) ^ ((o >> 3) & 7)) << 2) | (k & 3));
            Wv[adr] = (&v.x)[c];
        }
    }
    __syncthreads();

    const int w  = tid >> 6;              // wave = t (0..7)
    const int l  = tid & 63;
    const int q  = l >> 4;
    const int om = l & 15;
    const int t  = w;

    float acc[4][8];
    #pragma unroll
    for (int jj = 0; jj < 4; ++jj)
        #pragma unroll
        for (int nt = 0; nt < 8; ++nt) acc[jj][nt] = 0.f;

    for (int kc = 0; kc < 64; kc += 4) {
        float4 xv[4], wv[8];
        const int kx = kc ^ (q << 2);
        #pragma unroll
        for (int jj = 0; jj < 4; ++jj)
            xv[jj] = *(const float4*)&xs[(q * 4 + jj) * 512 + t * 64 + kx];
        #pragma unroll
        for (int nt = 0; nt < 8; ++nt) {
            int og  = nt * 16 + om;
            int grp = (kc >> 2) ^ ((nt * 2 + (om >> 3)) & 7);
            wv[nt]  = *(const float4*)&Wv[og * 68 + grp * 4];
        }
        #pragma unroll
        for (int jj = 0; jj < 4; ++jj) {
            #pragma unroll
            for (int nt = 0; nt < 8; ++nt) {
                float s = acc[jj][nt];
                s = fmaf(xv[jj].x, wv[nt].x, s);
                s = fmaf(xv[jj].y, wv[nt].y, s);
                s = fmaf(xv[jj].z, wv[nt].z, s);
                s = fmaf(xv[jj].w, wv[nt].w, s);
                acc[jj][nt] = s;
            }
        }
    }

    const int bt = b * 8 + t;

    float a1v[8], a2v[8];
    #pragma unroll
    for (int nt = 0; nt < 8; ++nt) {
        a1v[nt] = a[nt * 16 + om];
        a2v[nt] = a[128 + nt * 16 + om];
    }
    #pragma unroll
    for (int jj = 0; jj < 4; ++jj) {
        float s1 = 0.f, s2 = 0.f;
        #pragma unroll
        for (int nt = 0; nt < 8; ++nt) {
            s1 = fmaf(acc[jj][nt], a1v[nt], s1);
            s2 = fmaf(acc[jj][nt], a2v[nt], s2);
        }
        #pragma unroll
        for (int off = 1; off < 16; off <<= 1) {
            s1 += __shfl_xor(s1, off);
            s2 += __shfl_xor(s2, off);
        }
        if (om == 0) {
            int j = jt * 16 + q * 4 + jj;
            Wh1[bt * 1024 + j] = s1;
            Wh2[bt * 1024 + j] = s2;
        }
    }

    // 32x32x16 B-frag store
    #pragma unroll
    for (int nt = 0; nt < 8; ++nt) {
        uint2 st;
        st.x = pack_bf16(acc[0][nt], acc[1][nt]);
        st.y = pack_bf16(acc[2][nt], acc[3][nt]);
        int    lane2 = ((q >> 1) << 5) | ((nt & 1) << 4) | om;
        size_t fidx  = ((size_t)(bt * 4 + (nt >> 1)) * 64 + jt) * 64 + lane2;
        char*  p     = (char*)(Whf + fidx) + ((q & 1) << 3);
        *(uint2*)p = st;
    }
}

// ---------------------------------------------------------------------------
// Kernel 2: adj -> bitmask adjq for the 32x32 consumer (unchanged from r8):
//   jg = j>>3 decomposed jg = s4*4 + h*2 + g stored at i*128 + g*64 + h*32 + s4.
// ---------------------------------------------------------------------------
__global__ __launch_bounds__(256) void k_adjb(const float* __restrict__ adj,
                                              unsigned char* __restrict__ adjq) {
    int idx = blockIdx.x * 256 + threadIdx.x;       // 0..131071
    int i   = idx >> 7;
    int pos = idx & 127;                            // jg
    const float4* a4 = (const float4*)adj + idx * 2;
    float4 v0 = a4[0], v1 = a4[1];
    unsigned int by = 0;
    by |= (v0.x > 0.f) ? 1u : 0u;
    by |= (v0.y > 0.f) ? 2u : 0u;
    by |= (v0.z > 0.f) ? 4u : 0u;
    by |= (v0.w > 0.f) ? 8u : 0u;
    by |= (v1.x > 0.f) ? 16u : 0u;
    by |= (v1.y > 0.f) ? 32u : 0u;
    by |= (v1.z > 0.f) ? 64u : 0u;
    by |= (v1.w > 0.f) ? 128u : 0u;
    adjq[(i << 7) + ((pos & 1) << 6) + (((pos >> 1) & 1) << 5) + (pos >> 2)] = (unsigned char)by;
}

// ---------------------------------------------------------------------------
// Kernel 3: k_agg — dense flash aggregation, ROUND-9 P-build diet:
//   p = exp(lrelu(h1+h2) - mp) = max(A*E, B*F)   (exp monotone => exact)
//   A = exp(h1-mp), B = exp(.2h1-mp); E = exp(h2), F = exp(.2h2) staged as
//   SEPARATE fp32 LDS arrays (no unpack); mask applied via bfe+cvt+mul
//   (no vcc chains). ~8.5 VALU/element vs ~14-16 in r8.
// Supersteps of 128 j (8 barriers, 32 KB double buffer).
// Layouts (verified r8): A/B idx=lane&31, k=(lane>>5)*8+e; D col=lane&31,
// row=(reg&3)+8*(reg>>2)+4*(lane>>5). l_i via ones-MFMA.
// Grid 512: blockIdx = ((itile*8 + t)*8 + b) -> XCD = b.
// ---------------------------------------------------------------------------
__global__ __launch_bounds__(256) void k_agg(const uint4* __restrict__ Whf,
                                             const float* __restrict__ Wh1,
                                             const float* __restrict__ Wh2,
                                             const unsigned char* __restrict__ adjq,
                                             float* __restrict__ out) {
    __shared__ __attribute__((aligned(16))) uint4 bstage[2][2048];  // 64 KB
    __shared__ __attribute__((aligned(16))) float efsE[1024];       // 4 KB
    __shared__ __attribute__((aligned(16))) float efsF[1024];       // 4 KB
    __shared__ float wh1s[128];
    __shared__ float m2s[4];

    const int tid   = threadIdx.x;
    const int b     = blockIdx.x & 7;
    const int t     = (blockIdx.x >> 3) & 7;
    const int itile = blockIdx.x >> 6;            // 0..7
    const int bt    = b * 8 + t;
    const int i0    = itile * 128;

    const int w   = tid >> 6;                     // wave 0..3 (= ntile chunk)
    const int l   = tid & 63;
    const int col = l & 31;
    const int g   = l >> 5;                       // k-half group
    const int row = w * 32 + col;                 // block-local i-row

    const uint4* plane = Whf + (size_t)bt * 16384;

    // prefetch superstep 0 (kf 0..7 of this wave's ntile chunk)
    uint4 pf[8];
    #pragma unroll
    for (int f = 0; f < 8; ++f) pf[f] = plane[(w * 64 + f) * 64 + l];

    // adj mask regs: 64 B at (i0+row)*128 + g*64
    const uint4* ap = (const uint4*)(adjq + ((size_t)(i0 + row) << 7) + (g << 6));
    uint4 am[4];
    #pragma unroll
    for (int f = 0; f < 4; ++f) am[f] = ap[f];

    // stage E/F (separate fp32) + running max of h2; Wh1 slice
    const float* wh2g = Wh2 + bt * 1024;
    float mx = -1e30f;
    #pragma unroll
    for (int rep = 0; rep < 4; ++rep) {
        int   j  = tid + rep * 256;
        float h2 = wh2g[j];
        efsE[j] = __expf(h2);
        efsF[j] = __expf(ALPHA * h2);
        mx = fmaxf(mx, h2);
    }
    #pragma unroll
    for (int off = 1; off < 64; off <<= 1) mx = fmaxf(mx, __shfl_xor(mx, off));
    if (l == 0) m2s[w] = mx;
    if (tid < 128) wh1s[tid] = Wh1[bt * 1024 + i0 + tid];

    #pragma unroll
    for (int f = 0; f < 8; ++f) bstage[0][(w * 8 + f) * 64 + l] = pf[f];
    __syncthreads();

    const float M2 = fmaxf(fmaxf(m2s[0], m2s[1]), fmaxf(m2s[2], m2s[3]));
    const float h1 = wh1s[row];
    const float e0 = h1 + M2;
    const float mp = fmaxf(e0, ALPHA * e0);       // both products <= 1
    const float Af = __expf(h1 - mp);
    const float Bf = __expf(ALPHA * h1 - mp);

    f32x16 acc[4];
    #pragma unroll
    for (int nt2 = 0; nt2 < 4; ++nt2)
        #pragma unroll
        for (int r = 0; r < 16; ++r) acc[nt2][r] = 0.f;
    f32x16 accl;
    #pragma unroll
    for (int r = 0; r < 16; ++r) accl[r] = 0.f;

    bf16x8 ones;
    #pragma unroll
    for (int i = 0; i < 8; ++i) ones[i] = (short)0x3F80;

    #pragma unroll
    for (int u = 0; u < 8; ++u) {
        if (u + 1 < 8) {
            #pragma unroll
            for (int f = 0; f < 8; ++f)
                pf[f] = plane[(w * 64 + (u + 1) * 8 + f) * 64 + l];
        }

        #pragma unroll
        for (int ts = 0; ts < 8; ++ts) {          // 16-j MFMA slice
            const int jb = u * 128 + ts * 16 + g * 8;
            float4 E0 = *(const float4*)&efsE[jb];
            float4 E1 = *(const float4*)&efsE[jb + 4];
            float4 F0 = *(const float4*)&efsF[jb];
            float4 F1 = *(const float4*)&efsF[jb + 4];

            // adj byte (static select after full unroll)
            const int      pe = (ts & 1) * 32 + u * 4 + (ts >> 1);
            const uint4    av = am[pe >> 4];
            const int      cc = (pe >> 2) & 3;
            const uint32_t cw = (cc == 0) ? av.x : (cc == 1) ? av.y
                               : (cc == 2) ? av.z : av.w;
            const uint32_t by = (cw >> ((pe & 3) * 8)) & 0xFFu;

            float p[8];
            p[0] = fmaxf(Af * E0.x, Bf * F0.x) * (float)((by >> 0) & 1u);
            p[1] = fmaxf(Af * E0.y, Bf * F0.y) * (float)((by >> 1) & 1u);
            p[2] = fmaxf(Af * E0.z, Bf * F0.z) * (float)((by >> 2) & 1u);
            p[3] = fmaxf(Af * E0.w, Bf * F0.w) * (float)((by >> 3) & 1u);
            p[4] = fmaxf(Af * E1.x, Bf * F1.x) * (float)((by >> 4) & 1u);
            p[5] = fmaxf(Af * E1.y, Bf * F1.y) * (float)((by >> 5) & 1u);
            p[6] = fmaxf(Af * E1.z, Bf * F1.z) * (float)((by >> 6) & 1u);
            p[7] = fmaxf(Af * E1.w, Bf * F1.w) * (float)((by >> 7) & 1u);

            union { uint32_t u32[4]; bf16x8 v; } pk;
            #pragma unroll
            for (int r = 0; r < 4; ++r)
                pk.u32[r] = pack_bf16(p[2 * r], p[2 * r + 1]);

            #pragma unroll
            for (int nt2 = 0; nt2 < 4; ++nt2) {
                union { uint4 u4; bf16x8 v; } br;
                br.u4 = bstage[u & 1][(nt2 * 8 + ts) * 64 + l];
                acc[nt2] = __builtin_amdgcn_mfma_f32_32x32x16_bf16(
                    pk.v, br.v, acc[nt2], 0, 0, 0);
            }
            accl = __builtin_amdgcn_mfma_f32_32x32x16_bf16(
                pk.v, ones, accl, 0, 0, 0);
        }

        if (u + 1 < 8) {
            #pragma unroll
            for (int f = 0; f < 8; ++f)
                bstage[(u + 1) & 1][(w * 8 + f) * 64 + l] = pf[f];
        }
        __syncthreads();
    }

    // epilogue: D rows r = (reg&3)+8*(reg>>2)+4*g; accl rows identical
    float* og = out + ((size_t)(b * 1024 + i0 + w * 32)) * 1024 + t;
    #pragma unroll
    for (int reg = 0; reg < 16; ++reg) {
        const int   r    = (reg & 3) + 8 * (reg >> 2) + 4 * g;
        const float linv = 1.0f / accl[reg];
        #pragma unroll
        for (int nt2 = 0; nt2 < 4; ++nt2) {
            float v = acc[nt2][reg] * linv;
            v = v > 0.f ? v : __expf(v) - 1.f;
            og[(size_t)r * 1024 + (nt2 * 32 + col) * 8] = v;
        }
    }
}

// ---------------------------------------------------------------------------
extern "C" void kernel_launch(void* const* d_in, const int* in_sizes, int n_in,
                              void* d_out, int out_size, void* d_ws, size_t ws_size,
                              hipStream_t stream) {
    const float* x   = (const float*)d_in[0];   // (8,1024,64,8)
    const float* adj = (const float*)d_in[1];   // (1024,1024)
    const float* W   = (const float*)d_in[2];   // (64,128)
    const float* a   = (const float*)d_in[3];   // (256,1)
    float* out = (float*)d_out;                 // (8,1024,128,8)

    uint4*         Whf  = (uint4*)d_ws;                        // 1048576 uint4 = 16 MB
    float*         Wh1  = (float*)(Whf + 1048576);             // 65536 f
    float*         Wh2  = Wh1 + 65536;                         // 65536 f
    unsigned char* adjq = (unsigned char*)(Wh2 + 65536);       // 131072 B

    k_wh  <<<512, 512, 0, stream>>>(x, W, a, Whf, Wh1, Wh2);
    k_adjb<<<512, 256, 0, stream>>>(adj, adjq);
    k_agg <<<512, 256, 0, stream>>>(Whf, Wh1, Wh2, adjq, out);
}